// Round 5
// baseline (191.233 us; speedup 1.0000x reference)
//
#include <hip/hip_runtime.h>
#include <math.h>

#define BB 8
#define SS 128
#define NN 129
#define DD 256
#define HH 8
#define LN_EPS 1e-5f

// ws layout (float offsets)
#define OFF_A    0        // a:     [B][S][D]
#define OFF_BPT  262144   // bp_t:  [B][D][S]  (b_ + b_e1, transposed)
#define OFF_CPT  524288   // cp_t:  [B][D][S]  (a + b_ + b_e1, transposed)
#define OFF_VART 786432   // var_t: [B][D][S]  (nv[:,1:,:] transposed)
#define OFF_V    1048576  // v:     [B][N][D]
#define OFF_SQ   1312768  // sq:    [B][H][N]
#define OFF_SK   1321024  // sk:    [B][H][N]
#define OFF_MA   1329280
#define OFF_QA   1330304
#define OFF_MB   1331328
#define OFF_QB   1332352
#define OFF_MC   1333376
#define OFF_QC   1334400
#define OFF_U    1335424  // U: [D][H]
#define OFF_UB   1337472  // ubias: [H]

// ============ KA2: projections + stats + transposes + U-fold ================
// 2 barriers per block (vs ~10 in R4). Long unrolled loops, broadcast LDS rows.
__global__ __launch_bounds__(256) void ka2(
    const float* __restrict__ desc, const float* __restrict__ nv,
    const float* __restrict__ W_gt, const float* __restrict__ b_gt,
    const float* __restrict__ W_e1, const float* __restrict__ b_e1,
    const float* __restrict__ W_q, const float* __restrict__ b_q,
    const float* __restrict__ W_k, const float* __restrict__ b_k,
    const float* __restrict__ W_v, const float* __restrict__ b_v,
    const float* __restrict__ W_e2, const float* __restrict__ b_e2,
    const float* __restrict__ w_attn,
    float* __restrict__ a, float* __restrict__ bp_t, float* __restrict__ cp_t,
    float* __restrict__ var_t, float* __restrict__ v,
    float* __restrict__ sq, float* __restrict__ sk,
    float* __restrict__ ma, float* __restrict__ qa, float* __restrict__ mb,
    float* __restrict__ qb, float* __restrict__ mc, float* __restrict__ qc,
    float* __restrict__ U, float* __restrict__ ubias) {
    const int bx = blockIdx.x, t = threadIdx.x;
    __shared__ __attribute__((aligned(16))) float rowbuf[DD][4];
    __shared__ __attribute__((aligned(16))) float drow[DD][4];
    __shared__ float part[24][4];

    if (bx < 256) {
        // -------- part A: d = desc@W_gt+b_gt ; a = d@We1_t ; b = d@We1_b+be1
        const int b = bx >> 5, s0 = (bx & 31) * 4;
        for (int e = t; e < 4 * DD; e += 256) {
            int r = e >> 8, k = e & 255;
            rowbuf[k][r] = desc[(size_t)(b * SS + s0 + r) * DD + k];
        }
        __syncthreads();
        const int c = t;
        {
            float dv[4] = {0.f, 0.f, 0.f, 0.f};
#pragma unroll 8
            for (int k = 0; k < DD; k++) {
                float w = W_gt[k * DD + c];
                float4 d4 = *(const float4*)&rowbuf[k][0];
                dv[0] = fmaf(d4.x, w, dv[0]); dv[1] = fmaf(d4.y, w, dv[1]);
                dv[2] = fmaf(d4.z, w, dv[2]); dv[3] = fmaf(d4.w, w, dv[3]);
            }
            float bg = b_gt[c];
            float4 st; st.x = dv[0] + bg; st.y = dv[1] + bg; st.z = dv[2] + bg; st.w = dv[3] + bg;
            *(float4*)&drow[c][0] = st;
        }
        __syncthreads();
        float av[4] = {0.f, 0.f, 0.f, 0.f}, bv[4] = {0.f, 0.f, 0.f, 0.f};
#pragma unroll 4
        for (int k = 0; k < DD; k++) {
            float wa = W_e1[k * DD + c];
            float wb = W_e1[(DD + k) * DD + c];
            float4 d4 = *(const float4*)&drow[k][0];
            av[0] = fmaf(d4.x, wa, av[0]); av[1] = fmaf(d4.y, wa, av[1]);
            av[2] = fmaf(d4.z, wa, av[2]); av[3] = fmaf(d4.w, wa, av[3]);
            bv[0] = fmaf(d4.x, wb, bv[0]); bv[1] = fmaf(d4.y, wb, bv[1]);
            bv[2] = fmaf(d4.z, wb, bv[2]); bv[3] = fmaf(d4.w, wb, bv[3]);
        }
        float be1 = b_e1[c];
        float cv[4];
#pragma unroll
        for (int r = 0; r < 4; r++) { bv[r] += be1; cv[r] = av[r] + bv[r]; }
#pragma unroll
        for (int r = 0; r < 4; r++) a[(size_t)(b * SS + s0 + r) * DD + c] = av[r];
        float4 f4;
        f4.x = bv[0]; f4.y = bv[1]; f4.z = bv[2]; f4.w = bv[3];
        *(float4*)(bp_t + (size_t)(b * DD + c) * SS + s0) = f4;
        f4.x = cv[0]; f4.y = cv[1]; f4.z = cv[2]; f4.w = cv[3];
        *(float4*)(cp_t + (size_t)(b * DD + c) * SS + s0) = f4;
        float nvv[4];
#pragma unroll
        for (int r = 0; r < 4; r++) nvv[r] = nv[(size_t)(b * NN + 1 + s0 + r) * DD + c];
        f4.x = nvv[0]; f4.y = nvv[1]; f4.z = nvv[2]; f4.w = nvv[3];
        *(float4*)(var_t + (size_t)(b * DD + c) * SS + s0) = f4;
        // 24 block reductions: 4 rows x {sumA,sumA2,sumB,sumB2,sumC,sumC2}
        float vals[24];
#pragma unroll
        for (int r = 0; r < 4; r++) {
            vals[r * 6 + 0] = av[r]; vals[r * 6 + 1] = av[r] * av[r];
            vals[r * 6 + 2] = bv[r]; vals[r * 6 + 3] = bv[r] * bv[r];
            vals[r * 6 + 4] = cv[r]; vals[r * 6 + 5] = cv[r] * cv[r];
        }
        int lane = t & 63, wid = t >> 6;
#pragma unroll
        for (int vv = 0; vv < 24; vv++) {
            float x = vals[vv];
            for (int o = 32; o; o >>= 1) x += __shfl_xor(x, o, 64);
            if (lane == 0) part[vv][wid] = x;
        }
        __syncthreads();
        if (t < 24) {
            float ssum = (part[t][0] + part[t][1]) + (part[t][2] + part[t][3]);
            int st = t % 6;
            int row = b * SS + s0 + t / 6;
            float m = ssum * (1.f / DD);
            float* dstp = (st == 0) ? ma : (st == 1) ? qa : (st == 2) ? mb
                         : (st == 3) ? qb : (st == 4) ? mc : qc;
            dstp[row] = m;
        }
    } else if (bx < 520) {
        // -------- part B: q/k/v projections + collapsed sq/sk ---------------
        const int idx = bx - 256;
        const int b = idx / 33, n0 = (idx % 33) * 4;
        for (int e = t; e < 4 * DD; e += 256) {
            int r = e >> 8, k = e & 255;
            int n = n0 + r; if (n >= NN) n = NN - 1;
            rowbuf[k][r] = nv[(size_t)(b * NN + n) * DD + k];
        }
        __syncthreads();
        const int c = t;
        float qv[4] = {0.f, 0.f, 0.f, 0.f}, kv[4] = {0.f, 0.f, 0.f, 0.f},
              vv[4] = {0.f, 0.f, 0.f, 0.f};
#pragma unroll 4
        for (int k = 0; k < DD; k++) {
            float wq = W_q[k * DD + c], wk = W_k[k * DD + c], wvv = W_v[k * DD + c];
            float4 r4 = *(const float4*)&rowbuf[k][0];
            qv[0] = fmaf(r4.x, wq, qv[0]); qv[1] = fmaf(r4.y, wq, qv[1]);
            qv[2] = fmaf(r4.z, wq, qv[2]); qv[3] = fmaf(r4.w, wq, qv[3]);
            kv[0] = fmaf(r4.x, wk, kv[0]); kv[1] = fmaf(r4.y, wk, kv[1]);
            kv[2] = fmaf(r4.z, wk, kv[2]); kv[3] = fmaf(r4.w, wk, kv[3]);
            vv[0] = fmaf(r4.x, wvv, vv[0]); vv[1] = fmaf(r4.y, wvv, vv[1]);
            vv[2] = fmaf(r4.z, wvv, vv[2]); vv[3] = fmaf(r4.w, wvv, vv[3]);
        }
        float bq = b_q[c], bk = b_k[c], bvb = b_v[c];
        float waq = w_attn[c & 31];
        float wak = w_attn[32 + (c & 31)];
        int h = c >> 5;
#pragma unroll
        for (int r = 0; r < 4; r++) {
            int n = n0 + r;
            if (n < NN) v[(size_t)(b * NN + n) * DD + c] = vv[r] + bvb;
            float xq = (qv[r] + bq) * waq, xk = (kv[r] + bk) * wak;
#pragma unroll
            for (int o = 16; o; o >>= 1) { xq += __shfl_xor(xq, o); xk += __shfl_xor(xk, o); }
            if ((c & 31) == 0 && n < NN) {
                sq[(size_t)(b * HH + h) * NN + n] = xq;
                sk[(size_t)(b * HH + h) * NN + n] = xk;
            }
        }
    } else {
        // -------- part C: fold W_e2/we -> U, b_e2/we -> ubias ---------------
        const int ri = bx - 520;  // 0..63
        const int c = t;
        const float wec = w_attn[64 + (c & 31)];
#pragma unroll
        for (int rr = 0; rr < 4; rr++) {
            int r = ri * 4 + rr;
            float x = W_e2[(size_t)r * DD + c] * wec;
#pragma unroll
            for (int o = 16; o; o >>= 1) x += __shfl_xor(x, o);
            if ((c & 31) == 0) U[r * HH + (c >> 5)] = x;
        }
        if (ri == 0) {
            float x = b_e2[c] * wec;
#pragma unroll
            for (int o = 16; o; o >>= 1) x += __shfl_xor(x, o);
            if ((c & 31) == 0) ubias[c >> 5] = x;
        }
    }
}

// ============ KB2: adjacency + closed-form LN + relu + U-dot + softmax ======
// thread = (j-quad, d-octant): 32-iter loops, float4 loads, 48 VALU/load.
__global__ __launch_bounds__(256) void kb2(
    const float* __restrict__ a, const float* __restrict__ bp_t, const float* __restrict__ cp_t,
    const float* __restrict__ var_t, const float* __restrict__ nv,
    const float* __restrict__ ma, const float* __restrict__ qa,
    const float* __restrict__ mb, const float* __restrict__ qb,
    const float* __restrict__ mc, const float* __restrict__ qc,
    const float* __restrict__ sq, const float* __restrict__ sk,
    const float* __restrict__ ln_g, const float* __restrict__ ln_b,
    const float* __restrict__ U, const float* __restrict__ ubias,
    const float* __restrict__ b_attn,
    float* __restrict__ attn) {
    const int i = blockIdx.x, b = blockIdx.y;
    const int t = threadIdx.x, jq = t & 31, dg = t >> 5;
    __shared__ float Arow[DD];
    __shared__ float Vrow[DD];
    __shared__ float2 lnsm[DD];
    __shared__ __attribute__((aligned(16))) float4 Usm[DD][2];
    __shared__ __attribute__((aligned(16))) float rsm[SS], nmm[SS], mkm[SS], pnm[SS];
    __shared__ float sqb[HH], ubm[HH];
    __shared__ float sc[HH][132];
    __shared__ __attribute__((aligned(16))) float red[8][HH * SS];  // 32 KB, reused

    Arow[t] = (i >= 1) ? a[((size_t)b * SS + i - 1) * DD + t] : 0.f;
    Vrow[t] = nv[((size_t)b * NN + i) * DD + t];
    { float2 g; g.x = ln_g[t]; g.y = ln_b[t]; lnsm[t] = g; }
    Usm[t][0] = *(const float4*)&U[t * HH];
    Usm[t][1] = *(const float4*)&U[t * HH + 4];
    if (t < HH) {
        sqb[t] = sq[(size_t)b * HH * NN + t * NN + i] + b_attn[0];
        ubm[t] = ubias[t];
    }
    __syncthreads();

    // ---- pass 1: cross = a_i.b'_j ; dvv = nv_i.nv_j (per j-quad, d-octant)
    if (i >= 1) {
        float cr[4] = {0.f, 0.f, 0.f, 0.f}, dv[4] = {0.f, 0.f, 0.f, 0.f};
        const float* bc = bp_t + ((size_t)b * DD + dg * 32) * SS + 4 * jq;
        const float* vc = var_t + ((size_t)b * DD + dg * 32) * SS + 4 * jq;
#pragma unroll 8
        for (int dd = 0; dd < 32; dd++) {
            float4 b4 = *(const float4*)(bc + (size_t)dd * SS);
            float4 v4 = *(const float4*)(vc + (size_t)dd * SS);
            float A = Arow[dg * 32 + dd], V = Vrow[dg * 32 + dd];
            cr[0] = fmaf(A, b4.x, cr[0]); cr[1] = fmaf(A, b4.y, cr[1]);
            cr[2] = fmaf(A, b4.z, cr[2]); cr[3] = fmaf(A, b4.w, cr[3]);
            dv[0] = fmaf(V, v4.x, dv[0]); dv[1] = fmaf(V, v4.y, dv[1]);
            dv[2] = fmaf(V, v4.z, dv[2]); dv[3] = fmaf(V, v4.w, dv[3]);
        }
        float4 s0; s0.x = cr[0]; s0.y = cr[1]; s0.z = cr[2]; s0.w = cr[3];
        float4 s1; s1.x = dv[0]; s1.y = dv[1]; s1.z = dv[2]; s1.w = dv[3];
        *(float4*)&red[dg][4 * jq] = s0;
        *(float4*)&red[dg][SS + 4 * jq] = s1;
    }
    __syncthreads();
    if (t < SS) {
        const int j = t;
        float rs, nm, mk, pen;
        if (i == 0) {
            float mu = mc[b * SS + j], q2 = qc[b * SS + j];
            rs = rsqrtf(q2 - mu * mu + LN_EPS); nm = -mu * rs; mk = 1.f; pen = 0.f;
        } else {
            float cr = 0.f, dv = 0.f;
#pragma unroll
            for (int g = 0; g < 8; g++) { cr += red[g][j]; dv += red[g][SS + j]; }
            float muA = ma[b * SS + i - 1], qA = qa[b * SS + i - 1];
            float muB = mb[b * SS + j], qB = qb[b * SS + j];
            float mu = muA + muB;
            float var = qA + qB + 2.f * cr * (1.f / DD) - mu * mu;
            rs = rsqrtf(var + LN_EPS); nm = -mu * rs;
            mk = ((i - 1) != j && dv > 0.f) ? 1.f : 0.f;
            pen = (mk == 0.f) ? -1e9f : 0.f;
        }
        rsm[j] = rs; nmm[j] = nm; mkm[j] = mk; pnm[j] = pen;
    }
    __syncthreads();

    // ---- pass 2: LN + relu + 8-head U-dot ----
    float acc[4][HH];
#pragma unroll
    for (int jj = 0; jj < 4; jj++)
#pragma unroll
        for (int h = 0; h < HH; h++) acc[jj][h] = 0.f;
    {
        const float* Bp = ((i == 0) ? cp_t : bp_t) + ((size_t)b * DD + dg * 32) * SS + 4 * jq;
        float4 rs4 = *(const float4*)&rsm[4 * jq];
        float4 nm4 = *(const float4*)&nmm[4 * jq];
        float rsv[4] = {rs4.x, rs4.y, rs4.z, rs4.w};
        float nmv[4] = {nm4.x, nm4.y, nm4.z, nm4.w};
#pragma unroll 4
        for (int dd = 0; dd < 32; dd++) {
            const int d2 = dg * 32 + dd;
            float4 b4 = *(const float4*)(Bp + (size_t)dd * SS);
            float A = Arow[d2];
            float2 gb = lnsm[d2];
            float4 u0 = Usm[d2][0], u1 = Usm[d2][1];
            float bj[4] = {b4.x, b4.y, b4.z, b4.w};
#pragma unroll
            for (int jj = 0; jj < 4; jj++) {
                float y = fmaf(A + bj[jj], rsv[jj], nmv[jj]);
                y = fmaf(y, gb.x, gb.y);
                float rr = fmaxf(y, 0.f);
                acc[jj][0] = fmaf(rr, u0.x, acc[jj][0]);
                acc[jj][1] = fmaf(rr, u0.y, acc[jj][1]);
                acc[jj][2] = fmaf(rr, u0.z, acc[jj][2]);
                acc[jj][3] = fmaf(rr, u0.w, acc[jj][3]);
                acc[jj][4] = fmaf(rr, u1.x, acc[jj][4]);
                acc[jj][5] = fmaf(rr, u1.y, acc[jj][5]);
                acc[jj][6] = fmaf(rr, u1.z, acc[jj][6]);
                acc[jj][7] = fmaf(rr, u1.w, acc[jj][7]);
            }
        }
    }
    // partials: red[g][h*SS + j] (h-major: conflict-free float4 writes)
#pragma unroll
    for (int h = 0; h < HH; h++) {
        float4 w4;
        w4.x = acc[0][h]; w4.y = acc[1][h]; w4.z = acc[2][h]; w4.w = acc[3][h];
        *(float4*)&red[dg][h * SS + 4 * jq] = w4;
    }
    __syncthreads();
    // ---- reduce over d-octants + assemble scores ----
    {
        const int j = t >> 1, hb = (t & 1) * 4;
#pragma unroll
        for (int hh = 0; hh < 4; hh++) {
            int h = hb + hh;
            float s = 0.f;
#pragma unroll
            for (int g = 0; g < 8; g++) s += red[g][h * SS + j];
            float skv = sk[(size_t)b * HH * NN + h * NN + 1 + j];
            sc[h][1 + j] = sqb[h] + skv + (s + ubm[h]) * mkm[j] + pnm[j];
        }
    }
    if (t < HH) sc[t][0] = sqb[t] + sk[(size_t)b * HH * NN + t * NN] - 1e9f;
    __syncthreads();

    // ---- softmax + write: 32 lanes per head row ----
    {
        const int h = t >> 5, l = t & 31;
        float m = -INFINITY;
        for (int jj = l; jj < NN; jj += 32) m = fmaxf(m, sc[h][jj]);
#pragma unroll
        for (int o = 16; o; o >>= 1) m = fmaxf(m, __shfl_xor(m, o));
        float s = 0.f;
        for (int jj = l; jj < NN; jj += 32) { float e = __expf(sc[h][jj] - m); sc[h][jj] = e; s += e; }
#pragma unroll
        for (int o = 16; o; o >>= 1) s += __shfl_xor(s, o);
        float inv = 1.f / s;
        float* arow = attn + (((size_t)b * HH + h) * NN + i) * NN;
        for (int jj = l; jj < NN; jj += 32) arow[jj] = sc[h][jj] * inv;
    }
}

// ============ KC2: ctx = attn@v ; out = ctx@W_o + b_o (2-i tiles) ===========
__global__ __launch_bounds__(256) void kc2(
    const float* __restrict__ attn, const float* __restrict__ v,
    const float* __restrict__ W_o, const float* __restrict__ b_o,
    float* __restrict__ out) {
    const int b = blockIdx.y, i0 = blockIdx.x * 2;
    const int t = threadIdx.x;
    __shared__ float ar[2][HH * 132];
    __shared__ __attribute__((aligned(8))) float csm[DD][2];
    for (int e = t; e < 2 * HH * NN; e += 256) {
        int il = e / (HH * NN), r = e - il * (HH * NN);
        int h = r / NN, j = r - h * NN;
        int i = i0 + il; if (i >= NN) i = NN - 1;
        ar[il][h * 132 + j] = attn[(((size_t)b * HH + h) * NN + i) * NN + j];
    }
    __syncthreads();
    {
        const int d = t, h = d >> 5;
        float c0 = 0.f, c1 = 0.f;
        const float* vp = v + (size_t)b * NN * DD + d;
#pragma unroll 4
        for (int j = 0; j < NN; j++) {
            float vv = vp[(size_t)j * DD];
            c0 = fmaf(ar[0][h * 132 + j], vv, c0);
            c1 = fmaf(ar[1][h * 132 + j], vv, c1);
        }
        csm[d][0] = c0; csm[d][1] = c1;
    }
    __syncthreads();
    {
        const int c = t;
        float o0 = 0.f, o1 = 0.f;
#pragma unroll 8
        for (int k = 0; k < DD; k++) {
            float w = W_o[(size_t)k * DD + c];
            float2 cv = *(const float2*)&csm[k][0];
            o0 = fmaf(cv.x, w, o0); o1 = fmaf(cv.y, w, o1);
        }
        float bo = b_o[c];
        out[((size_t)b * NN + i0) * DD + c] = o0 + bo;
        if (i0 + 1 < NN) out[((size_t)b * NN + i0 + 1) * DD + c] = o1 + bo;
    }
}

extern "C" void kernel_launch(void* const* d_in, const int* in_sizes, int n_in,
                              void* d_out, int out_size, void* d_ws, size_t ws_size,
                              hipStream_t stream) {
    const float* desc   = (const float*)d_in[0];
    const float* nv     = (const float*)d_in[1];
    const float* W_gt   = (const float*)d_in[2];
    const float* b_gt   = (const float*)d_in[3];
    // d_in[4] topo_bias unused: sigmoid(x)>0 always, so adjacency sign = sample_sim sign
    const float* W_q    = (const float*)d_in[5];
    const float* b_q    = (const float*)d_in[6];
    const float* W_k    = (const float*)d_in[7];
    const float* b_k    = (const float*)d_in[8];
    const float* W_v    = (const float*)d_in[9];
    const float* b_v    = (const float*)d_in[10];
    const float* W_e1   = (const float*)d_in[11];
    const float* b_e1   = (const float*)d_in[12];
    const float* ln_g   = (const float*)d_in[13];
    const float* ln_b   = (const float*)d_in[14];
    const float* W_e2   = (const float*)d_in[15];
    const float* b_e2   = (const float*)d_in[16];
    const float* w_attn = (const float*)d_in[17];
    const float* b_attn = (const float*)d_in[18];
    const float* W_o    = (const float*)d_in[19];
    const float* b_o    = (const float*)d_in[20];

    float* ws   = (float*)d_ws;
    float* a    = ws + OFF_A;
    float* bp_t = ws + OFF_BPT;
    float* cp_t = ws + OFF_CPT;
    float* vart = ws + OFF_VART;
    float* v    = ws + OFF_V;
    float* sq   = ws + OFF_SQ;
    float* sk   = ws + OFF_SK;
    float* ma   = ws + OFF_MA;
    float* qa   = ws + OFF_QA;
    float* mb   = ws + OFF_MB;
    float* qb   = ws + OFF_QB;
    float* mc   = ws + OFF_MC;
    float* qc   = ws + OFF_QC;
    float* U    = ws + OFF_U;
    float* ub   = ws + OFF_UB;

    float* out  = (float*)d_out;
    float* attn = (float*)d_out + (size_t)BB * NN * DD;

    // KA2: 256 (desc proj) + 264 (qkv) + 64 (U fold) = 584 blocks
    ka2<<<dim3(584), dim3(256), 0, stream>>>(
        desc, nv, W_gt, b_gt, W_e1, b_e1, W_q, b_q, W_k, b_k, W_v, b_v,
        W_e2, b_e2, w_attn,
        a, bp_t, cp_t, vart, v, sq, sk, ma, qa, mb, qb, mc, qc, U, ub);
    kb2<<<dim3(NN, BB), dim3(256), 0, stream>>>(
        a, bp_t, cp_t, vart, nv, ma, qa, mb, qb, mc, qc, sq, sk,
        ln_g, ln_b, U, ub, b_attn, attn);
    kc2<<<dim3((NN + 1) / 2, BB), dim3(256), 0, stream>>>(attn, v, W_o, b_o, out);
}